// Round 1
// baseline (9408.005 us; speedup 1.0000x reference)
//
#include <hip/hip_runtime.h>
#include <cstdint>
#include <math.h>

#define T_TOTAL 4096
#define S_LEN   2048
#define NH      32
#define NKV     8
#define HD      128
#define HIDDEN  4096
#define QSZ     4096
#define KVSZ    1024
#define QKV_N   6144
#define SCALE_F 0.08838834764831843f   // 128^-0.5

typedef __bf16 bf16x8 __attribute__((ext_vector_type(8)));
typedef float  f32x4  __attribute__((ext_vector_type(4)));
typedef unsigned short u16;
typedef unsigned int   u32;
typedef u16 u16x8 __attribute__((ext_vector_type(8)));

__device__ __forceinline__ u16 f2bf(float f) {
  u32 b = __float_as_uint(f);
  b += 0x7FFFu + ((b >> 16) & 1u);      // round-to-nearest-even
  return (u16)(b >> 16);
}

// ---------------- fp32 -> bf16 cast (vectorized) ----------------
__global__ __launch_bounds__(256) void cast_bf16_kernel(const float4* __restrict__ in,
                                                        ushort4* __restrict__ out, int n4) {
  int i = blockIdx.x * 256 + threadIdx.x;
  if (i >= n4) return;
  float4 v = in[i];
  ushort4 o;
  o.x = f2bf(v.x); o.y = f2bf(v.y); o.z = f2bf(v.z); o.w = f2bf(v.w);
  out[i] = o;
}

// ---------------- fp32 [R][C] -> bf16 [C][R] transpose-cast ----------------
__global__ __launch_bounds__(256) void transpose_cast_kernel(const float* __restrict__ in,
                                                             u16* __restrict__ out, int R, int C) {
  __shared__ float tile[32][33];
  int bx = blockIdx.x * 32;  // col base in input
  int by = blockIdx.y * 32;  // row base in input
  int tx = threadIdx.x & 31, ty = threadIdx.x >> 5;
  for (int i = ty; i < 32; i += 8)
    tile[i][tx] = in[(size_t)(by + i) * C + bx + tx];
  __syncthreads();
  for (int i = ty; i < 32; i += 8)
    out[(size_t)(bx + i) * R + by + tx] = f2bf(tile[tx][i]);
}

// ---------------- bf16 MFMA GEMM: C[M][N] = A[M][K] * Bt[N][K]^T + bias ----------------
// 128x128 block tile, BK=32, 256 threads (4 waves), each wave owns 64x64 (4x4 16x16 frags)
__global__ __launch_bounds__(256) void gemm_bt_kernel(const u16* __restrict__ A,
                                                      const u16* __restrict__ Bt,
                                                      const float* __restrict__ bias,
                                                      float* __restrict__ C,
                                                      int M, int N, int K) {
  __shared__ u16 sA[128 * 32];
  __shared__ u16 sB[128 * 32];
  const int tid  = threadIdx.x;
  const int lane = tid & 63, wave = tid >> 6;
  const int quad = lane >> 4, l16 = lane & 15;
  const int wm = (wave >> 1) * 64, wn = (wave & 1) * 64;
  const int bm = blockIdx.y, bn = blockIdx.x;

  f32x4 acc[4][4] = {};

  for (int kt = 0; kt < K; kt += 32) {
    u16x8 va[2], vb[2];
#pragma unroll
    for (int i = 0; i < 2; ++i) {
      int c = i * 256 + tid;
      int row = c >> 2, col8 = (c & 3) * 8;
      va[i] = *(const u16x8*)(A  + (size_t)(bm * 128 + row) * K + kt + col8);
      vb[i] = *(const u16x8*)(Bt + (size_t)(bn * 128 + row) * K + kt + col8);
    }
    __syncthreads();   // previous iteration's LDS reads are done
#pragma unroll
    for (int i = 0; i < 2; ++i) {
      int c = i * 256 + tid;
      *(u16x8*)&sA[c * 8] = va[i];
      *(u16x8*)&sB[c * 8] = vb[i];
    }
    __syncthreads();   // staging visible

    bf16x8 af[4], bfr[4];
#pragma unroll
    for (int i = 0; i < 4; ++i)
      af[i] = *(const bf16x8*)&sA[(wm + i * 16 + l16) * 32 + quad * 8];
#pragma unroll
    for (int j = 0; j < 4; ++j)
      bfr[j] = *(const bf16x8*)&sB[(wn + j * 16 + l16) * 32 + quad * 8];
#pragma unroll
    for (int i = 0; i < 4; ++i)
#pragma unroll
      for (int j = 0; j < 4; ++j)
        acc[i][j] = __builtin_amdgcn_mfma_f32_16x16x32_bf16(af[i], bfr[j], acc[i][j], 0, 0, 0);
  }

#pragma unroll
  for (int i = 0; i < 4; ++i) {
    int row0 = bm * 128 + wm + i * 16 + quad * 4;
#pragma unroll
    for (int j = 0; j < 4; ++j) {
      int col = bn * 128 + wn + j * 16 + l16;
      float bi = bias[col];
#pragma unroll
      for (int r = 0; r < 4; ++r)
        C[(size_t)(row0 + r) * N + col] = acc[i][j][r] + bi;
    }
  }
}

// ---------------- NeoX RoPE, in-place on fp32 qkv [T][6144] ----------------
__global__ __launch_bounds__(256) void rope_kernel(float* __restrict__ qkv,
                                                   const int* __restrict__ pos) {
  int idx = blockIdx.x * 256 + threadIdx.x;            // T * 40 heads * 64 pairs
  int t = idx / 2560;
  int rem = idx - t * 2560;
  int head = rem >> 6, i = rem & 63;
  size_t base = (size_t)t * QKV_N + (head < NH ? head * HD : QSZ + (head - NH) * HD);
  float p = (float)pos[t];
  float inv = powf(100000.0f, -(float)(2 * i) * (1.0f / 128.0f));
  float f = p * inv;
  float s, c;
  sincosf(f, &s, &c);
  float x1 = qkv[base + i], x2 = qkv[base + 64 + i];
  qkv[base + i]      = x1 * c - x2 * s;
  qkv[base + 64 + i] = x2 * c + x1 * s;
}

// ---------------- fp32 flash attention (causal, GQA 4:1), bf16 output ----------------
// block: (q-tile of 32, head, batch); 256 threads
__global__ __launch_bounds__(256) void flash_kernel(const float* __restrict__ qkv,
                                                    u16* __restrict__ attn) {
  const int qt = blockIdx.x, h = blockIdx.y, b = blockIdx.z;
  const int kvh = h >> 2;
  const int tid = threadIdx.x;
  __shared__ float sQ[32][128], sK[32][128], sV[32][128], sP[32][32];
  __shared__ float sM[32], sL[32], sAl[32];

  for (int idx = tid; idx < 4096; idx += 256) {
    int r = idx >> 7, d = idx & 127;
    int t = b * S_LEN + qt * 32 + r;
    sQ[r][d] = qkv[(size_t)t * QKV_N + h * HD + d] * SCALE_F;
  }
  if (tid < 32) { sM[tid] = -INFINITY; sL[tid] = 0.0f; }

  const int r_s = tid >> 3, cg = tid & 7;
  const int d0 = (tid & 7) * 16;
  float acc[16];
#pragma unroll
  for (int i = 0; i < 16; ++i) acc[i] = 0.0f;

  for (int kt = 0; kt <= qt; ++kt) {
    for (int idx = tid; idx < 4096; idx += 256) {
      int r = idx >> 7, d = idx & 127;
      size_t rowoff = (size_t)(b * S_LEN + kt * 32 + r) * QKV_N;
      sK[r][d] = qkv[rowoff + QSZ + kvh * HD + d];
      sV[r][d] = qkv[rowoff + QSZ + KVSZ + kvh * HD + d];
    }
    __syncthreads();

    {
      const float4* qr = (const float4*)sQ[r_s];
      const float4* k0 = (const float4*)sK[cg * 4 + 0];
      const float4* k1 = (const float4*)sK[cg * 4 + 1];
      const float4* k2 = (const float4*)sK[cg * 4 + 2];
      const float4* k3 = (const float4*)sK[cg * 4 + 3];
      float s0 = 0.f, s1 = 0.f, s2 = 0.f, s3 = 0.f;
#pragma unroll 4
      for (int d4 = 0; d4 < 32; ++d4) {
        float4 q = qr[d4];
        float4 a = k0[d4]; s0 += q.x*a.x + q.y*a.y + q.z*a.z + q.w*a.w;
        float4 e = k1[d4]; s1 += q.x*e.x + q.y*e.y + q.z*e.z + q.w*e.w;
        float4 f = k2[d4]; s2 += q.x*f.x + q.y*f.y + q.z*f.z + q.w*f.w;
        float4 g = k3[d4]; s3 += q.x*g.x + q.y*g.y + q.z*g.z + q.w*g.w;
      }
      if (kt == qt) {
        int cb = cg * 4;
        if (cb + 0 > r_s) s0 = -1e30f;
        if (cb + 1 > r_s) s1 = -1e30f;
        if (cb + 2 > r_s) s2 = -1e30f;
        if (cb + 3 > r_s) s3 = -1e30f;
      }
      sP[r_s][cg * 4 + 0] = s0;
      sP[r_s][cg * 4 + 1] = s1;
      sP[r_s][cg * 4 + 2] = s2;
      sP[r_s][cg * 4 + 3] = s3;
    }
    __syncthreads();

    if (tid < 32) {
      float mOld = sM[tid];
      float mx = mOld;
#pragma unroll 8
      for (int c = 0; c < 32; ++c) mx = fmaxf(mx, sP[tid][c]);
      float alpha = __expf(mOld - mx);   // exp(-inf)=0 on first tile
      float sum = 0.0f;
#pragma unroll 8
      for (int c = 0; c < 32; ++c) { float p = __expf(sP[tid][c] - mx); sP[tid][c] = p; sum += p; }
      sM[tid] = mx;
      sL[tid] = sL[tid] * alpha + sum;
      sAl[tid] = alpha;
    }
    __syncthreads();

    float al = sAl[r_s];
#pragma unroll
    for (int i = 0; i < 16; ++i) acc[i] *= al;
#pragma unroll 4
    for (int j = 0; j < 32; ++j) {
      float p = sP[r_s][j];
      const float4* vr = (const float4*)&sV[j][d0];
      float4 v0 = vr[0], v1 = vr[1], v2 = vr[2], v3 = vr[3];
      acc[0]  += p*v0.x; acc[1]  += p*v0.y; acc[2]  += p*v0.z; acc[3]  += p*v0.w;
      acc[4]  += p*v1.x; acc[5]  += p*v1.y; acc[6]  += p*v1.z; acc[7]  += p*v1.w;
      acc[8]  += p*v2.x; acc[9]  += p*v2.y; acc[10] += p*v2.z; acc[11] += p*v2.w;
      acc[12] += p*v3.x; acc[13] += p*v3.y; acc[14] += p*v3.z; acc[15] += p*v3.w;
    }
    __syncthreads();
  }

  float invl = 1.0f / sL[r_s];
  int t = b * S_LEN + qt * 32 + r_s;
  size_t obase = (size_t)t * QSZ + h * HD + d0;
#pragma unroll
  for (int i = 0; i < 16; ++i) attn[obase + i] = f2bf(acc[i] * invl);
}

extern "C" void kernel_launch(void* const* d_in, const int* in_sizes, int n_in,
                              void* d_out, int out_size, void* d_ws, size_t ws_size,
                              hipStream_t stream) {
  const float* hidden    = (const float*)d_in[0];
  const int*   positions = (const int*)d_in[1];
  const float* w_qkv     = (const float*)d_in[2];
  const float* b_qkv     = (const float*)d_in[3];
  const float* w_o       = (const float*)d_in[4];
  const float* b_o       = (const float*)d_in[5];
  float* out = (float*)d_out;

  char* ws = (char*)d_ws;
  u16*   hb    = (u16*)ws;                                    // 32 MB
  u16*   wqT   = (u16*)(ws + (size_t)32  * 1024 * 1024);      // 48 MB  [6144][4096]
  u16*   woT   = (u16*)(ws + (size_t)80  * 1024 * 1024);      // 32 MB  [4096][4096]
  float* qkv   = (float*)(ws + (size_t)112 * 1024 * 1024);    // 96 MB  [4096][6144]
  u16*   attnb = (u16*)(ws + (size_t)208 * 1024 * 1024);      // 32 MB  [4096][4096]

  cast_bf16_kernel<<<T_TOTAL * HIDDEN / 4 / 256, 256, 0, stream>>>(
      (const float4*)hidden, (ushort4*)hb, T_TOTAL * HIDDEN / 4);
  transpose_cast_kernel<<<dim3(QKV_N / 32, HIDDEN / 32), 256, 0, stream>>>(w_qkv, wqT, HIDDEN, QKV_N);
  transpose_cast_kernel<<<dim3(HIDDEN / 32, QSZ / 32), 256, 0, stream>>>(w_o, woT, QSZ, HIDDEN);
  gemm_bt_kernel<<<dim3(QKV_N / 128, T_TOTAL / 128), 256, 0, stream>>>(
      hb, wqT, b_qkv, qkv, T_TOTAL, QKV_N, HIDDEN);
  rope_kernel<<<T_TOTAL * 2560 / 256, 256, 0, stream>>>(qkv, positions);
  flash_kernel<<<dim3(S_LEN / 32, NH, 2), 256, 0, stream>>>(qkv, attnb);
  gemm_bt_kernel<<<dim3(HIDDEN / 128, T_TOTAL / 128), 256, 0, stream>>>(
      attnb, woT, b_o, out, T_TOTAL, HIDDEN, QSZ);
}

// Round 2
// 1145.752 us; speedup vs baseline: 8.2112x; 8.2112x over previous
//
#include <hip/hip_runtime.h>
#include <cstdint>
#include <math.h>

#define T_TOTAL 4096
#define S_LEN   2048
#define NH      32
#define NKV     8
#define HD      128
#define HIDDEN  4096
#define QSZ     4096
#define KVSZ    1024
#define QKV_N   6144
#define SCALE_F 0.08838834764831843f   // 128^-0.5

typedef __bf16 bf16x8 __attribute__((ext_vector_type(8)));
typedef float  f32x4  __attribute__((ext_vector_type(4)));
typedef unsigned short u16;
typedef unsigned int   u32;
typedef u16 u16x8 __attribute__((ext_vector_type(8)));

__device__ __forceinline__ u16 f2bf(float f) {
  u32 b = __float_as_uint(f);
  b += 0x7FFFu + ((b >> 16) & 1u);      // round-to-nearest-even
  return (u16)(b >> 16);
}

// ---------------- fp32 -> bf16 cast (vectorized) ----------------
__global__ __launch_bounds__(256) void cast_bf16_kernel(const float4* __restrict__ in,
                                                        ushort4* __restrict__ out, int n4) {
  int i = blockIdx.x * 256 + threadIdx.x;
  if (i >= n4) return;
  float4 v = in[i];
  ushort4 o;
  o.x = f2bf(v.x); o.y = f2bf(v.y); o.z = f2bf(v.z); o.w = f2bf(v.w);
  out[i] = o;
}

// ---------------- fp32 [R][C] -> bf16 [C][R] transpose-cast ----------------
__global__ __launch_bounds__(256) void transpose_cast_kernel(const float* __restrict__ in,
                                                             u16* __restrict__ out, int R, int C) {
  __shared__ float tile[32][33];
  int bx = blockIdx.x * 32;  // col base in input
  int by = blockIdx.y * 32;  // row base in input
  int tx = threadIdx.x & 31, ty = threadIdx.x >> 5;
  for (int i = ty; i < 32; i += 8)
    tile[i][tx] = in[(size_t)(by + i) * C + bx + tx];
  __syncthreads();
  for (int i = ty; i < 32; i += 8)
    out[(size_t)(bx + i) * R + by + tx] = f2bf(tile[tx][i]);
}

// ---------------- bf16 MFMA GEMM: C[M][N] = A[M][K] * Bt[N][K]^T + bias ----------------
__global__ __launch_bounds__(256) void gemm_bt_kernel(const u16* __restrict__ A,
                                                      const u16* __restrict__ Bt,
                                                      const float* __restrict__ bias,
                                                      float* __restrict__ C,
                                                      int M, int N, int K) {
  __shared__ u16 sA[128 * 32];
  __shared__ u16 sB[128 * 32];
  const int tid  = threadIdx.x;
  const int lane = tid & 63, wave = tid >> 6;
  const int quad = lane >> 4, l16 = lane & 15;
  const int wm = (wave >> 1) * 64, wn = (wave & 1) * 64;
  const int bm = blockIdx.y, bn = blockIdx.x;

  f32x4 acc[4][4] = {};

  for (int kt = 0; kt < K; kt += 32) {
    u16x8 va[2], vb[2];
#pragma unroll
    for (int i = 0; i < 2; ++i) {
      int c = i * 256 + tid;
      int row = c >> 2, col8 = (c & 3) * 8;
      va[i] = *(const u16x8*)(A  + (size_t)(bm * 128 + row) * K + kt + col8);
      vb[i] = *(const u16x8*)(Bt + (size_t)(bn * 128 + row) * K + kt + col8);
    }
    __syncthreads();
#pragma unroll
    for (int i = 0; i < 2; ++i) {
      int c = i * 256 + tid;
      *(u16x8*)&sA[c * 8] = va[i];
      *(u16x8*)&sB[c * 8] = vb[i];
    }
    __syncthreads();

    bf16x8 af[4], bfr[4];
#pragma unroll
    for (int i = 0; i < 4; ++i)
      af[i] = *(const bf16x8*)&sA[(wm + i * 16 + l16) * 32 + quad * 8];
#pragma unroll
    for (int j = 0; j < 4; ++j)
      bfr[j] = *(const bf16x8*)&sB[(wn + j * 16 + l16) * 32 + quad * 8];
#pragma unroll
    for (int i = 0; i < 4; ++i)
#pragma unroll
      for (int j = 0; j < 4; ++j)
        acc[i][j] = __builtin_amdgcn_mfma_f32_16x16x32_bf16(af[i], bfr[j], acc[i][j], 0, 0, 0);
  }

#pragma unroll
  for (int i = 0; i < 4; ++i) {
    int row0 = bm * 128 + wm + i * 16 + quad * 4;
#pragma unroll
    for (int j = 0; j < 4; ++j) {
      int col = bn * 128 + wn + j * 16 + l16;
      float bi = bias[col];
#pragma unroll
      for (int r = 0; r < 4; ++r)
        C[(size_t)(row0 + r) * N + col] = acc[i][j][r] + bi;
    }
  }
}

// ---------------- RoPE + cast + layout for Q,K (bf16), scale folded into Q ----------------
__global__ __launch_bounds__(256) void qk_rope_cast_kernel(const float* __restrict__ qkv,
                                                           const int* __restrict__ pos,
                                                           u16* __restrict__ Qb,
                                                           u16* __restrict__ Kb) {
  int idx = blockIdx.x * 256 + threadIdx.x;   // T * 40 heads * 64 pairs
  int t = idx / 2560;
  int rem = idx - t * 2560;
  int head = rem >> 6, i = rem & 63;
  int b = t >> 11, s = t & 2047;
  float p = (float)pos[t];
  float inv = powf(100000.0f, -(float)(2 * i) * (1.0f / 128.0f));
  float f = p * inv;
  float sn, cs;
  sincosf(f, &sn, &cs);
  if (head < NH) {
    const float* src = qkv + (size_t)t * QKV_N + head * HD;
    float x1 = src[i], x2 = src[i + 64];
    u16* dst = Qb + (((size_t)(b * NH + head)) * S_LEN + s) * HD;
    dst[i]      = f2bf((x1 * cs - x2 * sn) * SCALE_F);
    dst[i + 64] = f2bf((x2 * cs + x1 * sn) * SCALE_F);
  } else {
    int kh = head - NH;
    const float* src = qkv + (size_t)t * QKV_N + QSZ + kh * HD;
    float x1 = src[i], x2 = src[i + 64];
    u16* dst = Kb + (((size_t)(b * NKV + kh)) * S_LEN + s) * HD;
    dst[i]      = f2bf(x1 * cs - x2 * sn);
    dst[i + 64] = f2bf(x2 * cs + x1 * sn);
  }
}

// ---------------- V transpose-cast: fp32 qkv -> bf16 Vtb [b][kvh][d=128][s=2048] ----------------
__global__ __launch_bounds__(256) void v_transpose_cast_kernel(const float* __restrict__ qkv,
                                                               u16* __restrict__ Vtb) {
  __shared__ float tile[32][33];
  int st = blockIdx.x * 32;
  int dt = blockIdx.y * 32;
  int bk = blockIdx.z;                      // b*8 + kvh
  int b = bk >> 3, kvh = bk & 7;
  int tx = threadIdx.x & 31, ty = threadIdx.x >> 5;
  const float* src = qkv + (size_t)(b * S_LEN) * QKV_N + QSZ + KVSZ + kvh * HD;
  for (int i = ty; i < 32; i += 8)
    tile[i][tx] = src[(size_t)(st + i) * QKV_N + dt + tx];
  __syncthreads();
  u16* dst = Vtb + (size_t)bk * HD * S_LEN;
  for (int i = ty; i < 32; i += 8)
    dst[(size_t)(dt + i) * S_LEN + st + tx] = f2bf(tile[tx][i]);
}

// ---------------- MFMA flash attention (causal, GQA 4:1) ----------------
// block = 256 threads (4 waves); Q-tile 64 (16 rows/wave); K-tile 64
__global__ __launch_bounds__(256) void flash_mfma_kernel(const u16* __restrict__ Qb,
                                                         const u16* __restrict__ Kb,
                                                         const u16* __restrict__ Vtb,
                                                         u16* __restrict__ attn) {
  const int qti = gridDim.x - 1 - blockIdx.x;   // long blocks launch first
  const int h = blockIdx.y, b = blockIdx.z;
  const int kvh = h >> 2;
  const int tid = threadIdx.x;
  const int lane = tid & 63, wave = tid >> 6;
  const int quad = lane >> 4, l16 = lane & 15;

  __shared__ u16 sK[64 * 136];     // padded: 136 u16/row -> 2-way-free bank pattern
  __shared__ u16 sVt[128 * 72];
  __shared__ u16 sP[4][16 * 72];   // wave-private P (C-layout -> A-layout round-trip)

  // Q fragments (A-layout): wave's 16 q-rows, held in registers for the whole kernel
  bf16x8 qf[4];
  {
    const u16* qrow = Qb + (((size_t)(b * NH + h)) * S_LEN + (size_t)qti * 64 + wave * 16 + l16) * HD;
#pragma unroll
    for (int kc = 0; kc < 4; ++kc)
      qf[kc] = *(const bf16x8*)(qrow + kc * 32 + quad * 8);
  }

  f32x4 acc[8] = {};
  float m_r[4] = {-INFINITY, -INFINITY, -INFINITY, -INFINITY};
  float l_r[4] = {0.f, 0.f, 0.f, 0.f};

  const u16* Kbase = Kb  + ((size_t)(b * NKV + kvh)) * S_LEN * HD;
  const u16* Vbase = Vtb + ((size_t)(b * NKV + kvh)) * HD * S_LEN;

  for (int kt = 0; kt <= qti; ++kt) {
    // stage K tile: 64 rows x 128 d
#pragma unroll
    for (int i = 0; i < 4; ++i) {
      int c = i * 256 + tid;
      int row = c >> 4, col8 = (c & 15) * 8;
      *(u16x8*)&sK[row * 136 + col8] =
          *(const u16x8*)(Kbase + (size_t)(kt * 64 + row) * HD + col8);
    }
    // stage Vt tile: 128 d x 64 k
#pragma unroll
    for (int i = 0; i < 4; ++i) {
      int c = i * 256 + tid;
      int row = c >> 3, col8 = (c & 7) * 8;
      *(u16x8*)&sVt[row * 72 + col8] =
          *(const u16x8*)(Vbase + (size_t)row * S_LEN + kt * 64 + col8);
    }
    __syncthreads();

    // QK^T: 16x64 scores per wave
    f32x4 s[4] = {};
#pragma unroll
    for (int kc = 0; kc < 4; ++kc) {
#pragma unroll
      for (int nb = 0; nb < 4; ++nb) {
        bf16x8 kf = *(const bf16x8*)&sK[(nb * 16 + l16) * 136 + kc * 32 + quad * 8];
        s[nb] = __builtin_amdgcn_mfma_f32_16x16x32_bf16(qf[kc], kf, s[nb], 0, 0, 0);
      }
    }

    if (kt == qti) {   // causal mask on diagonal tile
#pragma unroll
      for (int nb = 0; nb < 4; ++nb) {
        int kcol = nb * 16 + l16;
#pragma unroll
        for (int r = 0; r < 4; ++r) {
          int qrow = wave * 16 + quad * 4 + r;
          if (kcol > qrow) s[nb][r] = -1e30f;
        }
      }
    }

    // online softmax; row r lives across the 16 lanes of this quad-group
    float alpha[4];
#pragma unroll
    for (int r = 0; r < 4; ++r) {
      float mx = fmaxf(fmaxf(s[0][r], s[1][r]), fmaxf(s[2][r], s[3][r]));
#pragma unroll
      for (int off = 8; off >= 1; off >>= 1)
        mx = fmaxf(mx, __shfl_xor(mx, off));
      float mnew = fmaxf(m_r[r], mx);
      alpha[r] = __expf(m_r[r] - mnew);
      m_r[r] = mnew;
      float p0 = __expf(s[0][r] - mnew);
      float p1 = __expf(s[1][r] - mnew);
      float p2 = __expf(s[2][r] - mnew);
      float p3 = __expf(s[3][r] - mnew);
      s[0][r] = p0; s[1][r] = p1; s[2][r] = p2; s[3][r] = p3;
      float rs = p0 + p1 + p2 + p3;
#pragma unroll
      for (int off = 8; off >= 1; off >>= 1)
        rs += __shfl_xor(rs, off);
      l_r[r] = l_r[r] * alpha[r] + rs;
    }

#pragma unroll
    for (int db = 0; db < 8; ++db)
#pragma unroll
      for (int r = 0; r < 4; ++r)
        acc[db][r] *= alpha[r];

    // P: C-layout regs -> wave-private LDS (bf16) -> A-layout frags
    u16* sPw = sP[wave];
#pragma unroll
    for (int nb = 0; nb < 4; ++nb)
#pragma unroll
      for (int r = 0; r < 4; ++r)
        sPw[(quad * 4 + r) * 72 + nb * 16 + l16] = f2bf(s[nb][r]);

#pragma unroll
    for (int ch = 0; ch < 2; ++ch) {
      bf16x8 pf = *(const bf16x8*)&sPw[l16 * 72 + ch * 32 + quad * 8];
#pragma unroll
      for (int db = 0; db < 8; ++db) {
        bf16x8 vf = *(const bf16x8*)&sVt[(db * 16 + l16) * 72 + ch * 32 + quad * 8];
        acc[db] = __builtin_amdgcn_mfma_f32_16x16x32_bf16(pf, vf, acc[db], 0, 0, 0);
      }
    }
    __syncthreads();
  }

  // epilogue: normalize, bf16 store
#pragma unroll
  for (int r = 0; r < 4; ++r) {
    int q = qti * 64 + wave * 16 + quad * 4 + r;
    float invl = 1.0f / l_r[r];
    size_t obase = ((size_t)(b * S_LEN + q)) * QSZ + (size_t)h * HD;
#pragma unroll
    for (int db = 0; db < 8; ++db)
      attn[obase + db * 16 + l16] = f2bf(acc[db][r] * invl);
  }
}

extern "C" void kernel_launch(void* const* d_in, const int* in_sizes, int n_in,
                              void* d_out, int out_size, void* d_ws, size_t ws_size,
                              hipStream_t stream) {
  const float* hidden    = (const float*)d_in[0];
  const int*   positions = (const int*)d_in[1];
  const float* w_qkv     = (const float*)d_in[2];
  const float* b_qkv     = (const float*)d_in[3];
  const float* w_o       = (const float*)d_in[4];
  const float* b_o       = (const float*)d_in[5];
  float* out = (float*)d_out;

  char* ws = (char*)d_ws;
  const size_t MB = 1024 * 1024;
  u16*   hb    = (u16*)ws;                       // 0..32 MB   (gemm1 A)
  u16*   wqT   = (u16*)(ws + 32  * MB);          // 32..80 MB  (gemm1 B)
  u16*   woT   = (u16*)(ws + 80  * MB);          // 80..112 MB (gemm2 B)
  float* qkv   = (float*)(ws + 112 * MB);        // 112..208 MB
  u16*   attnb = (u16*)(ws + 208 * MB);          // 208..240 MB
  // overlays — alive only after gemm1 has consumed hb/wqT:
  u16*   Qb    = (u16*)ws;                       // 0..32 MB
  u16*   Kb    = (u16*)(ws + 32 * MB);           // 32..40 MB
  u16*   Vtb   = (u16*)(ws + 40 * MB);           // 40..48 MB

  cast_bf16_kernel<<<T_TOTAL * HIDDEN / 4 / 256, 256, 0, stream>>>(
      (const float4*)hidden, (ushort4*)hb, T_TOTAL * HIDDEN / 4);
  transpose_cast_kernel<<<dim3(QKV_N / 32, HIDDEN / 32), 256, 0, stream>>>(w_qkv, wqT, HIDDEN, QKV_N);
  transpose_cast_kernel<<<dim3(HIDDEN / 32, QSZ / 32), 256, 0, stream>>>(w_o, woT, QSZ, HIDDEN);
  gemm_bt_kernel<<<dim3(QKV_N / 128, T_TOTAL / 128), 256, 0, stream>>>(
      hb, wqT, b_qkv, qkv, T_TOTAL, QKV_N, HIDDEN);
  qk_rope_cast_kernel<<<T_TOTAL * 2560 / 256, 256, 0, stream>>>(qkv, positions, Qb, Kb);
  v_transpose_cast_kernel<<<dim3(S_LEN / 32, HD / 32, 16), 256, 0, stream>>>(qkv, Vtb);
  flash_mfma_kernel<<<dim3(S_LEN / 64, NH, 2), 256, 0, stream>>>(Qb, Kb, Vtb, attnb);
  gemm_bt_kernel<<<dim3(HIDDEN / 128, T_TOTAL / 128), 256, 0, stream>>>(
      attnb, woT, b_o, out, T_TOTAL, HIDDEN, QSZ);
}

// Round 4
// 1116.426 us; speedup vs baseline: 8.4269x; 1.0263x over previous
//
#include <hip/hip_runtime.h>
#include <cstdint>
#include <math.h>

#define T_TOTAL 4096
#define S_LEN   2048
#define NH      32
#define NKV     8
#define HD      128
#define HIDDEN  4096
#define QSZ     4096
#define KVSZ    1024
#define QKV_N   6144
#define SCALE_F 0.08838834764831843f   // 128^-0.5

typedef __bf16 bf16x8 __attribute__((ext_vector_type(8)));
typedef float  f32x4  __attribute__((ext_vector_type(4)));
typedef unsigned short u16;
typedef unsigned int   u32;
typedef u16 u16x8 __attribute__((ext_vector_type(8)));

__device__ __forceinline__ u16 f2bf(float f) {
  u32 b = __float_as_uint(f);
  b += 0x7FFFu + ((b >> 16) & 1u);      // round-to-nearest-even
  return (u16)(b >> 16);
}

// async global->LDS, 16B per lane; LDS dst MUST be uniform base + lane*16
__device__ __forceinline__ void async_copy16(const u16* g, u16* l) {
  __builtin_amdgcn_global_load_lds(
      (const __attribute__((address_space(1))) void*)(g),
      (__attribute__((address_space(3))) void*)(l), 16, 0, 0);
}

// ---------------- fp32 -> bf16 cast (vectorized) ----------------
__global__ __launch_bounds__(256) void cast_bf16_kernel(const float4* __restrict__ in,
                                                        ushort4* __restrict__ out, int n4) {
  int i = blockIdx.x * 256 + threadIdx.x;
  if (i >= n4) return;
  float4 v = in[i];
  ushort4 o;
  o.x = f2bf(v.x); o.y = f2bf(v.y); o.z = f2bf(v.z); o.w = f2bf(v.w);
  out[i] = o;
}

// ---------------- fp32 [R][C] -> bf16 [C][R] transpose-cast ----------------
__global__ __launch_bounds__(256) void transpose_cast_kernel(const float* __restrict__ in,
                                                             u16* __restrict__ out, int R, int C) {
  __shared__ float tile[32][33];
  int bx = blockIdx.x * 32;
  int by = blockIdx.y * 32;
  int tx = threadIdx.x & 31, ty = threadIdx.x >> 5;
  for (int i = ty; i < 32; i += 8)
    tile[i][tx] = in[(size_t)(by + i) * C + bx + tx];
  __syncthreads();
  for (int i = ty; i < 32; i += 8)
    out[(size_t)(bx + i) * R + by + tx] = f2bf(tile[tx][i]);
}

// ---------------- bf16 MFMA GEMM (m97 structure): C = A * Bt^T + bias ----------------
// 128x128 tile, BK=32, 256 threads, global_load_lds width-16 staging
__global__ __launch_bounds__(256) void gemm_bt_kernel(const u16* __restrict__ A,
                                                      const u16* __restrict__ Bt,
                                                      const float* __restrict__ bias,
                                                      float* __restrict__ C,
                                                      int M, int N, int K) {
  __shared__ u16 sA[128 * 32];
  __shared__ u16 sB[128 * 32];
  const int tid  = threadIdx.x;
  const int lane = tid & 63, wave = tid >> 6;
  const int quad = lane >> 4, l16 = lane & 15;
  const int wm = (wave >> 1) * 64, wn = (wave & 1) * 64;
  const int bm = blockIdx.y, bn = blockIdx.x;

  const u16* gA0 = A  + (size_t)(bm * 128 + (tid >> 2)) * K + (tid & 3) * 8;
  const u16* gA1 = gA0 + (size_t)64 * K;
  const u16* gB0 = Bt + (size_t)(bn * 128 + (tid >> 2)) * K + (tid & 3) * 8;
  const u16* gB1 = gB0 + (size_t)64 * K;
  u16* lA0 = &sA[(size_t)tid * 8];
  u16* lA1 = &sA[(size_t)(256 + tid) * 8];
  u16* lB0 = &sB[(size_t)tid * 8];
  u16* lB1 = &sB[(size_t)(256 + tid) * 8];

  f32x4 acc[4][4] = {};

  for (int kt = 0; kt < K; kt += 32) {
    __syncthreads();   // previous iteration's LDS reads are done
    async_copy16(gA0 + kt, lA0);
    async_copy16(gA1 + kt, lA1);
    async_copy16(gB0 + kt, lB0);
    async_copy16(gB1 + kt, lB1);
    __syncthreads();   // drains vmcnt: staging visible

    bf16x8 af[4], bfr[4];
#pragma unroll
    for (int i = 0; i < 4; ++i)
      af[i] = *(const bf16x8*)&sA[(wm + i * 16 + l16) * 32 + quad * 8];
#pragma unroll
    for (int j = 0; j < 4; ++j)
      bfr[j] = *(const bf16x8*)&sB[(wn + j * 16 + l16) * 32 + quad * 8];
#pragma unroll
    for (int i = 0; i < 4; ++i)
#pragma unroll
      for (int j = 0; j < 4; ++j)
        acc[i][j] = __builtin_amdgcn_mfma_f32_16x16x32_bf16(af[i], bfr[j], acc[i][j], 0, 0, 0);
  }

#pragma unroll
  for (int i = 0; i < 4; ++i) {
    int row0 = bm * 128 + wm + i * 16 + quad * 4;
#pragma unroll
    for (int j = 0; j < 4; ++j) {
      int col = bn * 128 + wn + j * 16 + l16;
      float bi = bias[col];
#pragma unroll
      for (int r = 0; r < 4; ++r)
        C[(size_t)(row0 + r) * N + col] = acc[i][j][r] + bi;
    }
  }
}

// ---------------- RoPE + cast + layout for Q,K (bf16), scale folded into Q ----------------
__global__ __launch_bounds__(256) void qk_rope_cast_kernel(const float* __restrict__ qkv,
                                                           const int* __restrict__ pos,
                                                           u16* __restrict__ Qb,
                                                           u16* __restrict__ Kb) {
  int idx = blockIdx.x * 256 + threadIdx.x;   // T * 40 heads * 64 pairs
  int t = idx / 2560;
  int rem = idx - t * 2560;
  int head = rem >> 6, i = rem & 63;
  int b = t >> 11, s = t & 2047;
  float p = (float)pos[t];
  float inv = exp2f(-(float)i * 0.25952563f);   // (1e5)^(-2i/128)
  float f = p * inv;
  float sn, cs;
  sincosf(f, &sn, &cs);
  if (head < NH) {
    const float* src = qkv + (size_t)t * QKV_N + head * HD;
    float x1 = src[i], x2 = src[i + 64];
    u16* dst = Qb + (((size_t)(b * NH + head)) * S_LEN + s) * HD;
    dst[i]      = f2bf((x1 * cs - x2 * sn) * SCALE_F);
    dst[i + 64] = f2bf((x2 * cs + x1 * sn) * SCALE_F);
  } else {
    int kh = head - NH;
    const float* src = qkv + (size_t)t * QKV_N + QSZ + kh * HD;
    float x1 = src[i], x2 = src[i + 64];
    u16* dst = Kb + (((size_t)(b * NKV + kh)) * S_LEN + s) * HD;
    dst[i]      = f2bf(x1 * cs - x2 * sn);
    dst[i + 64] = f2bf(x2 * cs + x1 * sn);
  }
}

// ---------------- V transpose-cast: fp32 qkv -> bf16 Vtb [b][kvh][d=128][s=2048] ----------------
__global__ __launch_bounds__(256) void v_transpose_cast_kernel(const float* __restrict__ qkv,
                                                               u16* __restrict__ Vtb) {
  __shared__ float tile[32][33];
  int st = blockIdx.x * 32;
  int dt = blockIdx.y * 32;
  int bk = blockIdx.z;                      // b*8 + kvh
  int b = bk >> 3, kvh = bk & 7;
  int tx = threadIdx.x & 31, ty = threadIdx.x >> 5;
  const float* src = qkv + (size_t)(b * S_LEN) * QKV_N + QSZ + KVSZ + kvh * HD;
  for (int i = ty; i < 32; i += 8)
    tile[i][tx] = src[(size_t)(st + i) * QKV_N + dt + tx];
  __syncthreads();
  u16* dst = Vtb + (size_t)bk * HD * S_LEN;
  for (int i = ty; i < 32; i += 8)
    dst[(size_t)(dt + i) * S_LEN + st + tx] = f2bf(tile[tx][i]);
}

// ---------------- MFMA flash attention (causal, GQA 4:1), register-prefetch K-loop ----------------
__global__ __launch_bounds__(256) void flash_mfma_kernel(const u16* __restrict__ Qb,
                                                         const u16* __restrict__ Kb,
                                                         const u16* __restrict__ Vtb,
                                                         u16* __restrict__ attn) {
  const int qti = gridDim.x - 1 - blockIdx.x;   // long blocks launch first
  const int h = blockIdx.y, b = blockIdx.z;
  const int kvh = h >> 2;
  const int tid = threadIdx.x;
  const int lane = tid & 63, wave = tid >> 6;
  const int quad = lane >> 4, l16 = lane & 15;

  __shared__ u16 sK[64 * 136];
  __shared__ u16 sVt[128 * 72];
  __shared__ u16 sP[4][16 * 72];

  bf16x8 qf[4];
  {
    const u16* qrow = Qb + (((size_t)(b * NH + h)) * S_LEN + (size_t)qti * 64 + wave * 16 + l16) * HD;
#pragma unroll
    for (int kc = 0; kc < 4; ++kc)
      qf[kc] = *(const bf16x8*)(qrow + kc * 32 + quad * 8);
  }

  f32x4 acc[8] = {};
  float m_r[4] = {-INFINITY, -INFINITY, -INFINITY, -INFINITY};
  float l_r[4] = {0.f, 0.f, 0.f, 0.f};

  const u16* Kbase = Kb  + ((size_t)(b * NKV + kvh)) * S_LEN * HD;
  const u16* Vbase = Vtb + ((size_t)(b * NKV + kvh)) * HD * S_LEN;

  // register prefetch buffers for next K/V tile
  u16x8 kv[4], vv[4];
#pragma unroll
  for (int i = 0; i < 4; ++i) {
    int c = i * 256 + tid;
    kv[i] = *(const u16x8*)(Kbase + (size_t)(c >> 4) * HD + (c & 15) * 8);
    vv[i] = *(const u16x8*)(Vbase + (size_t)(c >> 3) * S_LEN + (c & 7) * 8);
  }

  for (int kt = 0; kt <= qti; ++kt) {
    __syncthreads();   // previous compute done, LDS reusable
#pragma unroll
    for (int i = 0; i < 4; ++i) {
      int c = i * 256 + tid;
      *(u16x8*)&sK[(c >> 4) * 136 + (c & 15) * 8] = kv[i];
      *(u16x8*)&sVt[(c >> 3) * 72 + (c & 7) * 8]  = vv[i];
    }
    __syncthreads();   // staging visible

    if (kt < qti) {    // prefetch next tile; vmcnt wait lands at next iter's LDS write
#pragma unroll
      for (int i = 0; i < 4; ++i) {
        int c = i * 256 + tid;
        kv[i] = *(const u16x8*)(Kbase + (size_t)((kt + 1) * 64 + (c >> 4)) * HD + (c & 15) * 8);
        vv[i] = *(const u16x8*)(Vbase + (size_t)(c >> 3) * S_LEN + (kt + 1) * 64 + (c & 7) * 8);
      }
    }

    // QK^T: 16x64 scores per wave
    f32x4 s[4] = {};
#pragma unroll
    for (int kc = 0; kc < 4; ++kc) {
#pragma unroll
      for (int nb = 0; nb < 4; ++nb) {
        bf16x8 kf = *(const bf16x8*)&sK[(nb * 16 + l16) * 136 + kc * 32 + quad * 8];
        s[nb] = __builtin_amdgcn_mfma_f32_16x16x32_bf16(qf[kc], kf, s[nb], 0, 0, 0);
      }
    }

    if (kt == qti) {   // causal mask on diagonal tile
#pragma unroll
      for (int nb = 0; nb < 4; ++nb) {
        int kcol = nb * 16 + l16;
#pragma unroll
        for (int r = 0; r < 4; ++r) {
          int qrow = wave * 16 + quad * 4 + r;
          if (kcol > qrow) s[nb][r] = -1e30f;
        }
      }
    }

    // online softmax; row r lives across the 16 lanes of this quad-group
    float alpha[4];
#pragma unroll
    for (int r = 0; r < 4; ++r) {
      float mx = fmaxf(fmaxf(s[0][r], s[1][r]), fmaxf(s[2][r], s[3][r]));
#pragma unroll
      for (int off = 8; off >= 1; off >>= 1)
        mx = fmaxf(mx, __shfl_xor(mx, off));
      float mnew = fmaxf(m_r[r], mx);
      alpha[r] = __expf(m_r[r] - mnew);
      m_r[r] = mnew;
      float p0 = __expf(s[0][r] - mnew);
      float p1 = __expf(s[1][r] - mnew);
      float p2 = __expf(s[2][r] - mnew);
      float p3 = __expf(s[3][r] - mnew);
      s[0][r] = p0; s[1][r] = p1; s[2][r] = p2; s[3][r] = p3;
      float rs = p0 + p1 + p2 + p3;
#pragma unroll
      for (int off = 8; off >= 1; off >>= 1)
        rs += __shfl_xor(rs, off);
      l_r[r] = l_r[r] * alpha[r] + rs;
    }

#pragma unroll
    for (int db = 0; db < 8; ++db)
#pragma unroll
      for (int r = 0; r < 4; ++r)
        acc[db][r] *= alpha[r];

    // P: C-layout regs -> wave-private LDS (bf16) -> A-layout frags
    u16* sPw = sP[wave];
#pragma unroll
    for (int nb = 0; nb < 4; ++nb)
#pragma unroll
      for (int r = 0; r < 4; ++r)
        sPw[(quad * 4 + r) * 72 + nb * 16 + l16] = f2bf(s[nb][r]);

#pragma unroll
    for (int ch = 0; ch < 2; ++ch) {
      bf16x8 pf = *(const bf16x8*)&sPw[l16 * 72 + ch * 32 + quad * 8];
#pragma unroll
      for (int db = 0; db < 8; ++db) {
        bf16x8 vf = *(const bf16x8*)&sVt[(db * 16 + l16) * 72 + ch * 32 + quad * 8];
        acc[db] = __builtin_amdgcn_mfma_f32_16x16x32_bf16(pf, vf, acc[db], 0, 0, 0);
      }
    }
  }

  // epilogue: normalize, bf16 store
#pragma unroll
  for (int r = 0; r < 4; ++r) {
    int q = qti * 64 + wave * 16 + quad * 4 + r;
    float invl = 1.0f / l_r[r];
    size_t obase = ((size_t)(b * S_LEN + q)) * QSZ + (size_t)h * HD;
#pragma unroll
    for (int db = 0; db < 8; ++db)
      attn[obase + db * 16 + l16] = f2bf(acc[db][r] * invl);
  }
}

extern "C" void kernel_launch(void* const* d_in, const int* in_sizes, int n_in,
                              void* d_out, int out_size, void* d_ws, size_t ws_size,
                              hipStream_t stream) {
  const float* hidden    = (const float*)d_in[0];
  const int*   positions = (const int*)d_in[1];
  const float* w_qkv     = (const float*)d_in[2];
  const float* b_qkv     = (const float*)d_in[3];
  const float* w_o       = (const float*)d_in[4];
  const float* b_o       = (const float*)d_in[5];
  float* out = (float*)d_out;

  char* ws = (char*)d_ws;
  const size_t MB = 1024 * 1024;
  u16*   hb    = (u16*)ws;                       // 0..32 MB   (gemm1 A)
  u16*   wqT   = (u16*)(ws + 32  * MB);          // 32..80 MB  (gemm1 B)
  u16*   woT   = (u16*)(ws + 80  * MB);          // 80..112 MB (gemm2 B)
  float* qkv   = (float*)(ws + 112 * MB);        // 112..208 MB
  u16*   attnb = (u16*)(ws + 208 * MB);          // 208..240 MB
  // overlays — alive only after gemm1 has consumed hb/wqT:
  u16*   Qb    = (u16*)ws;                       // 0..32 MB
  u16*   Kb    = (u16*)(ws + 32 * MB);           // 32..40 MB
  u16*   Vtb   = (u16*)(ws + 40 * MB);           // 40..48 MB

  cast_bf16_kernel<<<T_TOTAL * HIDDEN / 4 / 256, 256, 0, stream>>>(
      (const float4*)hidden, (ushort4*)hb, T_TOTAL * HIDDEN / 4);
  transpose_cast_kernel<<<dim3(QKV_N / 32, HIDDEN / 32), 256, 0, stream>>>(w_qkv, wqT, HIDDEN, QKV_N);
  transpose_cast_kernel<<<dim3(HIDDEN / 32, QSZ / 32), 256, 0, stream>>>(w_o, woT, QSZ, HIDDEN);
  gemm_bt_kernel<<<dim3(QKV_N / 128, T_TOTAL / 128), 256, 0, stream>>>(
      hb, wqT, b_qkv, qkv, T_TOTAL, QKV_N, HIDDEN);
  qk_rope_cast_kernel<<<T_TOTAL * 2560 / 256, 256, 0, stream>>>(qkv, positions, Qb, Kb);
  v_transpose_cast_kernel<<<dim3(S_LEN / 32, HD / 32, 16), 256, 0, stream>>>(qkv, Vtb);
  flash_mfma_kernel<<<dim3(S_LEN / 64, NH, 2), 256, 0, stream>>>(Qb, Kb, Vtb, attnb);
  gemm_bt_kernel<<<dim3(HIDDEN / 128, T_TOTAL / 128), 256, 0, stream>>>(
      attnb, woT, b_o, out, T_TOTAL, HIDDEN, QSZ);
}